// Round 1
// baseline (9445.518 us; speedup 1.0000x reference)
//
#include <hip/hip_runtime.h>
#include <hip/hip_bf16.h>

#define N_NODES 50000
#define N_EDGES 800000
#define F 256
#define NGRAPH 64
#define NCLS 16

// ---------------- degree / norm precompute ----------------

__global__ __launch_bounds__(256) void k_deg_init(int* __restrict__ deg) {
    int n = blockIdx.x * 256 + threadIdx.x;
    if (n < N_NODES) deg[n] = 1;   // self-loop
}

__global__ __launch_bounds__(256) void k_deg_edges(const int* __restrict__ dst,
                                                   int* __restrict__ deg) {
    int e = blockIdx.x * 256 + threadIdx.x;
    if (e < N_EDGES) atomicAdd(&deg[dst[e]], 1);
}

__global__ __launch_bounds__(256) void k_dinv(const int* __restrict__ deg,
                                              float* __restrict__ dinv) {
    int n = blockIdx.x * 256 + threadIdx.x;
    if (n < N_NODES) dinv[n] = rsqrtf((float)deg[n]);
}

__global__ __launch_bounds__(256) void k_norm(const int* __restrict__ src,
                                              const int* __restrict__ dst,
                                              const float* __restrict__ dinv,
                                              float* __restrict__ nrm) {
    int e = blockIdx.x * 256 + threadIdx.x;
    if (e < N_EDGES) nrm[e] = dinv[src[e]] * dinv[dst[e]];
}

// ---------------- GEMM 256x256 (f32 v0) ----------------
// block: 256 threads; covers 32 rows x 64 cols. grid = (ceil(N/32), 4)

__global__ __launch_bounds__(256) void k_gemm256(const float* __restrict__ A,
                                                 const float* __restrict__ W,
                                                 float* __restrict__ C) {
    __shared__ float As[32][257];   // +1 pad: row reads hit distinct banks
    const int rowBase = blockIdx.x * 32;
    const int cbase = blockIdx.y * 64;
    const int t = threadIdx.x;

    for (int i = t; i < 32 * 64; i += 256) {
        int r = i >> 6;
        int c4 = (i & 63) * 4;
        int row = rowBase + r;
        if (row >= N_NODES) row = N_NODES - 1;   // clamp (stores guarded below)
        const float4 v = *(const float4*)(A + (size_t)row * F + c4);
        As[r][c4 + 0] = v.x; As[r][c4 + 1] = v.y;
        As[r][c4 + 2] = v.z; As[r][c4 + 3] = v.w;
    }
    __syncthreads();

    const int tr = t >> 3;               // 0..31
    const int tc = cbase + (t & 7) * 8;  // 8 cols per thread
    float acc0 = 0.f, acc1 = 0.f, acc2 = 0.f, acc3 = 0.f;
    float acc4 = 0.f, acc5 = 0.f, acc6 = 0.f, acc7 = 0.f;

#pragma unroll 4
    for (int k = 0; k < 256; ++k) {
        float a = As[tr][k];
        const float4* wp = (const float4*)(W + (size_t)k * F + tc);
        float4 w0 = wp[0];
        float4 w1 = wp[1];
        acc0 += a * w0.x; acc1 += a * w0.y; acc2 += a * w0.z; acc3 += a * w0.w;
        acc4 += a * w1.x; acc5 += a * w1.y; acc6 += a * w1.z; acc7 += a * w1.w;
    }

    int row = rowBase + tr;
    if (row < N_NODES) {
        float4* op = (float4*)(C + (size_t)row * F + tc);
        op[0] = make_float4(acc0, acc1, acc2, acc3);
        op[1] = make_float4(acc4, acc5, acc6, acc7);
    }
}

// ---------------- self-loop + bias init: AGG = b + H * dinv^2 ----------------

__global__ __launch_bounds__(256) void k_init_agg(const float* __restrict__ H,
                                                  const float* __restrict__ bias,
                                                  const float* __restrict__ dinv,
                                                  float* __restrict__ AGG) {
    size_t idx = (size_t)blockIdx.x * 256 + threadIdx.x;  // float4 index
    if (idx >= (size_t)N_NODES * (F / 4)) return;
    int n = (int)(idx >> 6);
    int c4 = (int)(idx & 63) * 4;
    float s = dinv[n]; s = s * s;
    const float4 h = *(const float4*)(H + (size_t)n * F + c4);
    const float4 b = *(const float4*)(bias + c4);
    float4 o;
    o.x = b.x + h.x * s; o.y = b.y + h.y * s;
    o.z = b.z + h.z * s; o.w = b.w + h.w * s;
    *(float4*)(AGG + (size_t)n * F + c4) = o;
}

// ---------------- edge scatter-add (F=256): one wave per edge ----------------

__global__ __launch_bounds__(256) void k_scatter256(const float* __restrict__ H,
                                                    const int* __restrict__ src,
                                                    const int* __restrict__ dst,
                                                    const float* __restrict__ nrm,
                                                    float* __restrict__ AGG) {
    int gid = blockIdx.x * 256 + threadIdx.x;
    int e = gid >> 6;          // edge id (wave per edge)
    int lane = gid & 63;       // lane handles feats [4*lane, 4*lane+4)
    if (e >= N_EDGES) return;
    int s = src[e];
    int d = dst[e];
    float w = nrm[e];
    const float4 v = *(const float4*)(H + (size_t)s * F + lane * 4);
    float* p = AGG + (size_t)d * F + lane * 4;
    unsafeAtomicAdd(p + 0, v.x * w);
    unsafeAtomicAdd(p + 1, v.y * w);
    unsafeAtomicAdd(p + 2, v.z * w);
    unsafeAtomicAdd(p + 3, v.w * w);
}

// ---------------- elementwise ----------------

__global__ __launch_bounds__(256) void k_relu(const float* __restrict__ in,
                                              float* __restrict__ out) {
    size_t idx = ((size_t)blockIdx.x * 256 + threadIdx.x) * 4;
    if (idx >= (size_t)N_NODES * F) return;
    float4 v = *(const float4*)(in + idx);
    v.x = fmaxf(v.x, 0.f); v.y = fmaxf(v.y, 0.f);
    v.z = fmaxf(v.z, 0.f); v.w = fmaxf(v.w, 0.f);
    *(float4*)(out + idx) = v;
}

// out = relu(relu(agg) + hc)
__global__ __launch_bounds__(256) void k_combine(const float* __restrict__ agg,
                                                 const float* __restrict__ hc,
                                                 float* __restrict__ out) {
    size_t idx = ((size_t)blockIdx.x * 256 + threadIdx.x) * 4;
    if (idx >= (size_t)N_NODES * F) return;
    float4 a = *(const float4*)(agg + idx);
    float4 h = *(const float4*)(hc + idx);
    float4 o;
    o.x = fmaxf(fmaxf(a.x, 0.f) + h.x, 0.f);
    o.y = fmaxf(fmaxf(a.y, 0.f) + h.y, 0.f);
    o.z = fmaxf(fmaxf(a.z, 0.f) + h.z, 0.f);
    o.w = fmaxf(fmaxf(a.w, 0.f) + h.w, 0.f);
    *(float4*)(out + idx) = o;
}

// ---------------- layer 4: GEMM 256 -> 16 ----------------

__global__ __launch_bounds__(256) void k_gemm16(const float* __restrict__ A,
                                                const float* __restrict__ W4,
                                                float* __restrict__ C) {
    __shared__ float Ws[256][16];
    const int t = threadIdx.x;
    {
        const float4* wp = (const float4*)(W4 + (size_t)t * 16);
        float4 a = wp[0], b = wp[1], c = wp[2], d = wp[3];
        float4* sp = (float4*)&Ws[t][0];
        sp[0] = a; sp[1] = b; sp[2] = c; sp[3] = d;
    }
    __syncthreads();
    int row = blockIdx.x * 256 + t;
    if (row >= N_NODES) return;
    const float4* ap = (const float4*)(A + (size_t)row * F);
    float acc[16];
#pragma unroll
    for (int c = 0; c < 16; ++c) acc[c] = 0.f;
    for (int k4 = 0; k4 < 64; ++k4) {
        float4 a = ap[k4];
        float av[4] = {a.x, a.y, a.z, a.w};
#pragma unroll
        for (int j = 0; j < 4; ++j) {
            const float4* wr = (const float4*)&Ws[k4 * 4 + j][0];
            float4 w0 = wr[0], w1 = wr[1], w2 = wr[2], w3 = wr[3];
            acc[0]  += av[j] * w0.x; acc[1]  += av[j] * w0.y;
            acc[2]  += av[j] * w0.z; acc[3]  += av[j] * w0.w;
            acc[4]  += av[j] * w1.x; acc[5]  += av[j] * w1.y;
            acc[6]  += av[j] * w1.z; acc[7]  += av[j] * w1.w;
            acc[8]  += av[j] * w2.x; acc[9]  += av[j] * w2.y;
            acc[10] += av[j] * w2.z; acc[11] += av[j] * w2.w;
            acc[12] += av[j] * w3.x; acc[13] += av[j] * w3.y;
            acc[14] += av[j] * w3.z; acc[15] += av[j] * w3.w;
        }
    }
    float4* op = (float4*)(C + (size_t)row * 16);
    op[0] = make_float4(acc[0], acc[1], acc[2], acc[3]);
    op[1] = make_float4(acc[4], acc[5], acc[6], acc[7]);
    op[2] = make_float4(acc[8], acc[9], acc[10], acc[11]);
    op[3] = make_float4(acc[12], acc[13], acc[14], acc[15]);
}

__global__ __launch_bounds__(256) void k_init16(const float* __restrict__ H,
                                                const float* __restrict__ bias,
                                                const float* __restrict__ dinv,
                                                float* __restrict__ AGG) {
    int idx = blockIdx.x * 256 + threadIdx.x;   // float4 index
    if (idx >= N_NODES * 4) return;
    int n = idx >> 2;
    int c4 = (idx & 3) * 4;
    float s = dinv[n]; s = s * s;
    const float4 h = *(const float4*)(H + (size_t)n * 16 + c4);
    const float4 b = *(const float4*)(bias + c4);
    float4 o;
    o.x = b.x + h.x * s; o.y = b.y + h.y * s;
    o.z = b.z + h.z * s; o.w = b.w + h.w * s;
    *(float4*)(AGG + (size_t)n * 16 + c4) = o;
}

__global__ __launch_bounds__(256) void k_scatter16(const float* __restrict__ H,
                                                   const int* __restrict__ src,
                                                   const int* __restrict__ dst,
                                                   const float* __restrict__ nrm,
                                                   float* __restrict__ AGG) {
    int idx = blockIdx.x * 256 + threadIdx.x;
    int e = idx >> 2;
    int c4 = (idx & 3) * 4;
    if (e >= N_EDGES) return;
    int s = src[e];
    int d = dst[e];
    float w = nrm[e];
    const float4 v = *(const float4*)(H + (size_t)s * 16 + c4);
    float* p = AGG + (size_t)d * 16 + c4;
    unsafeAtomicAdd(p + 0, v.x * w);
    unsafeAtomicAdd(p + 1, v.y * w);
    unsafeAtomicAdd(p + 2, v.z * w);
    unsafeAtomicAdd(p + 3, v.w * w);
}

// ---------------- mean pool ----------------

__global__ __launch_bounds__(256) void k_pool_zero(float* __restrict__ pool,
                                                   float* __restrict__ cnt) {
    int i = blockIdx.x * 256 + threadIdx.x;
    if (i < NGRAPH * NCLS) pool[i] = 0.f;
    if (i < NGRAPH) cnt[i] = 0.f;
}

__global__ __launch_bounds__(256) void k_pool(const float* __restrict__ H4,
                                              const int* __restrict__ batch,
                                              float* __restrict__ pool,
                                              float* __restrict__ cnt) {
    __shared__ float ps[NGRAPH][NCLS];
    __shared__ float pc[NGRAPH];
    for (int i = threadIdx.x; i < NGRAPH * NCLS; i += 256) ((float*)ps)[i] = 0.f;
    if (threadIdx.x < NGRAPH) pc[threadIdx.x] = 0.f;
    __syncthreads();
    int n = blockIdx.x * 256 + threadIdx.x;
    if (n < N_NODES) {
        int g = batch[n];
        const float4* hp = (const float4*)(H4 + (size_t)n * 16);
        float4 a = hp[0], b = hp[1], c = hp[2], d = hp[3];
        atomicAdd(&ps[g][0],  a.x); atomicAdd(&ps[g][1],  a.y);
        atomicAdd(&ps[g][2],  a.z); atomicAdd(&ps[g][3],  a.w);
        atomicAdd(&ps[g][4],  b.x); atomicAdd(&ps[g][5],  b.y);
        atomicAdd(&ps[g][6],  b.z); atomicAdd(&ps[g][7],  b.w);
        atomicAdd(&ps[g][8],  c.x); atomicAdd(&ps[g][9],  c.y);
        atomicAdd(&ps[g][10], c.z); atomicAdd(&ps[g][11], c.w);
        atomicAdd(&ps[g][12], d.x); atomicAdd(&ps[g][13], d.y);
        atomicAdd(&ps[g][14], d.z); atomicAdd(&ps[g][15], d.w);
        atomicAdd(&pc[g], 1.f);
    }
    __syncthreads();
    for (int i = threadIdx.x; i < NGRAPH * NCLS; i += 256)
        unsafeAtomicAdd(&pool[i], ((float*)ps)[i]);
    if (threadIdx.x < NGRAPH) unsafeAtomicAdd(&cnt[threadIdx.x], pc[threadIdx.x]);
}

__global__ __launch_bounds__(256) void k_final(const float* __restrict__ pool,
                                               const float* __restrict__ cnt,
                                               float* __restrict__ out) {
    int i = blockIdx.x * 256 + threadIdx.x;
    if (i < NGRAPH * NCLS) out[i] = pool[i] / fmaxf(cnt[i >> 4], 1.f);
}

// ---------------- host ----------------

extern "C" void kernel_launch(void* const* d_in, const int* in_sizes, int n_in,
                              void* d_out, int out_size, void* d_ws, size_t ws_size,
                              hipStream_t stream) {
    const float* x   = (const float*)d_in[0];
    const int*   ei  = (const int*)d_in[1];      // [2][E]
    const int*   bvec= (const int*)d_in[2];
    const float* W1  = (const float*)d_in[3];
    const float* b1  = (const float*)d_in[4];
    const float* W2  = (const float*)d_in[5];
    const float* b2  = (const float*)d_in[6];
    const float* W3  = (const float*)d_in[7];
    const float* b3  = (const float*)d_in[8];
    const float* W4  = (const float*)d_in[9];
    const float* b4  = (const float*)d_in[10];
    float* out = (float*)d_out;

    const int* src = ei;
    const int* dst = ei + N_EDGES;

    const size_t NF = (size_t)N_NODES * F;
    float* ws = (float*)d_ws;
    float* P0   = ws;
    float* P1   = ws + NF;
    float* P2   = ws + 2 * NF;
    float* aux  = ws + 3 * NF;
    int*   degi = (int*)aux;                 // N ints
    float* dinv = aux + N_NODES;             // N floats
    float* nrm  = aux + 2 * N_NODES;         // E floats
    float* pool = aux + 2 * N_NODES + N_EDGES;
    float* cnt  = pool + NGRAPH * NCLS;

    const int BN   = (N_NODES + 255) / 256;        // 196
    const int BE   = (N_EDGES + 255) / 256;        // 3125
    const int BEL  = (N_EDGES * 64 + 255) / 256;   // 200000 (wave per edge)
    const int BNF4 = (int)((NF / 4 + 255) / 256);  // 12500
    const dim3 GG((N_NODES + 31) / 32, 4);

    // degrees + edge norms (shared by all layers)
    k_deg_init<<<BN, 256, 0, stream>>>(degi);
    k_deg_edges<<<BE, 256, 0, stream>>>(dst, degi);
    k_dinv<<<BN, 256, 0, stream>>>(degi, dinv);
    k_norm<<<BE, 256, 0, stream>>>(src, dst, dinv, nrm);

    // ---- layer 1: h1 = conv(x, W1, b1); P2 = relu(h1)
    k_gemm256<<<GG, 256, 0, stream>>>(x, W1, P0);
    k_init_agg<<<BNF4, 256, 0, stream>>>(P0, b1, dinv, P1);
    k_scatter256<<<BEL, 256, 0, stream>>>(P0, src, dst, nrm, P1);
    k_relu<<<BNF4, 256, 0, stream>>>(P1, P2);

    // ---- layer 2: h2 = conv(P2, W2, b2); P0 = relu(relu(h2) + P2)
    k_gemm256<<<GG, 256, 0, stream>>>(P2, W2, P0);
    k_init_agg<<<BNF4, 256, 0, stream>>>(P0, b2, dinv, P1);
    k_scatter256<<<BEL, 256, 0, stream>>>(P0, src, dst, nrm, P1);
    k_combine<<<BNF4, 256, 0, stream>>>(P1, P2, P0);

    // ---- layer 3: h3 = conv(P0, W3, b3); P2 = relu(relu(h3) + P0)
    k_gemm256<<<GG, 256, 0, stream>>>(P0, W3, P2);
    k_init_agg<<<BNF4, 256, 0, stream>>>(P2, b3, dinv, P1);
    k_scatter256<<<BEL, 256, 0, stream>>>(P2, src, dst, nrm, P1);
    k_combine<<<BNF4, 256, 0, stream>>>(P1, P0, P2);

    // ---- layer 4: h4 = conv(P2, W4, b4) -> [N,16] in P1
    k_gemm16<<<BN, 256, 0, stream>>>(P2, W4, P0);
    k_init16<<<(N_NODES * 4 + 255) / 256, 256, 0, stream>>>(P0, b4, dinv, P1);
    k_scatter16<<<(N_EDGES * 4 + 255) / 256, 256, 0, stream>>>(P0, src, dst, nrm, P1);

    // ---- mean pool
    k_pool_zero<<<5, 256, 0, stream>>>(pool, cnt);
    k_pool<<<BN, 256, 0, stream>>>(P1, bvec, pool, cnt);
    k_final<<<4, 256, 0, stream>>>(pool, cnt, out);
}

// Round 2
// 1624.776 us; speedup vs baseline: 5.8134x; 5.8134x over previous
//
#include <hip/hip_runtime.h>
#include <hip/hip_bf16.h>

#define N_NODES 50000
#define N_EDGES 800000
#define F 256
#define NGRAPH 64
#define NCLS 16
#define NBLK_N 196   // ceil(50000/256)

// ---------------- CSR build ----------------

__global__ __launch_bounds__(256) void k_zero_int(int* __restrict__ p, int n) {
    int i = blockIdx.x * 256 + threadIdx.x;
    if (i < n) p[i] = 0;
}

__global__ __launch_bounds__(256) void k_count(const int* __restrict__ dst,
                                               int* __restrict__ ecnt) {
    int e = blockIdx.x * 256 + threadIdx.x;
    if (e < N_EDGES) atomicAdd(&ecnt[dst[e]], 1);
}

__global__ __launch_bounds__(256) void k_dinv(const int* __restrict__ ecnt,
                                              float* __restrict__ dinv) {
    int n = blockIdx.x * 256 + threadIdx.x;
    if (n < N_NODES) dinv[n] = rsqrtf((float)(ecnt[n] + 1));  // +1 self-loop
}

// exclusive scan, 3-phase
__global__ __launch_bounds__(256) void k_scan_block(const int* __restrict__ ecnt,
                                                    int* __restrict__ rowptr,
                                                    int* __restrict__ blkSum) {
    __shared__ int sh[256];
    int i = blockIdx.x * 256 + threadIdx.x;
    int v = (i < N_NODES) ? ecnt[i] : 0;
    sh[threadIdx.x] = v;
    __syncthreads();
#pragma unroll
    for (int off = 1; off < 256; off <<= 1) {
        int t = (threadIdx.x >= off) ? sh[threadIdx.x - off] : 0;
        __syncthreads();
        sh[threadIdx.x] += t;
        __syncthreads();
    }
    if (i < N_NODES) rowptr[i] = sh[threadIdx.x] - v;  // exclusive within block
    if (threadIdx.x == 255) blkSum[blockIdx.x] = sh[255];
}

__global__ __launch_bounds__(256) void k_scan_tops(int* __restrict__ blkSum,
                                                   int* __restrict__ blkOff) {
    __shared__ int sh[256];
    int v = (threadIdx.x < NBLK_N) ? blkSum[threadIdx.x] : 0;
    sh[threadIdx.x] = v;
    __syncthreads();
#pragma unroll
    for (int off = 1; off < 256; off <<= 1) {
        int t = (threadIdx.x >= off) ? sh[threadIdx.x - off] : 0;
        __syncthreads();
        sh[threadIdx.x] += t;
        __syncthreads();
    }
    if (threadIdx.x < NBLK_N) blkOff[threadIdx.x] = sh[threadIdx.x] - v;
}

__global__ __launch_bounds__(256) void k_scan_add(int* __restrict__ rowptr,
                                                  const int* __restrict__ blkOff,
                                                  int* __restrict__ cursor) {
    int i = blockIdx.x * 256 + threadIdx.x;
    if (i < N_NODES) {
        int r = rowptr[i] + blkOff[blockIdx.x];
        rowptr[i] = r;
        cursor[i] = r;
    }
    if (i == 0) rowptr[N_NODES] = N_EDGES;
}

__global__ __launch_bounds__(256) void k_fill_csr(const int* __restrict__ src,
                                                  const int* __restrict__ dst,
                                                  const float* __restrict__ dinv,
                                                  int* __restrict__ cursor,
                                                  int* __restrict__ csr_src,
                                                  float* __restrict__ csr_w) {
    int e = blockIdx.x * 256 + threadIdx.x;
    if (e >= N_EDGES) return;
    int s = src[e];
    int d = dst[e];
    int p = atomicAdd(&cursor[d], 1);
    csr_src[p] = s;
    csr_w[p] = dinv[s] * dinv[d];
}

// ---------------- GEMM 256x256 (f32) ----------------

__global__ __launch_bounds__(256) void k_gemm256(const float* __restrict__ A,
                                                 const float* __restrict__ W,
                                                 float* __restrict__ C) {
    __shared__ float As[32][257];
    const int rowBase = blockIdx.x * 32;
    const int cbase = blockIdx.y * 64;
    const int t = threadIdx.x;

    for (int i = t; i < 32 * 64; i += 256) {
        int r = i >> 6;
        int c4 = (i & 63) * 4;
        int row = rowBase + r;
        if (row >= N_NODES) row = N_NODES - 1;
        const float4 v = *(const float4*)(A + (size_t)row * F + c4);
        As[r][c4 + 0] = v.x; As[r][c4 + 1] = v.y;
        As[r][c4 + 2] = v.z; As[r][c4 + 3] = v.w;
    }
    __syncthreads();

    const int tr = t >> 3;
    const int tc = cbase + (t & 7) * 8;
    float acc0 = 0.f, acc1 = 0.f, acc2 = 0.f, acc3 = 0.f;
    float acc4 = 0.f, acc5 = 0.f, acc6 = 0.f, acc7 = 0.f;

#pragma unroll 4
    for (int k = 0; k < 256; ++k) {
        float a = As[tr][k];
        const float4* wp = (const float4*)(W + (size_t)k * F + tc);
        float4 w0 = wp[0];
        float4 w1 = wp[1];
        acc0 += a * w0.x; acc1 += a * w0.y; acc2 += a * w0.z; acc3 += a * w0.w;
        acc4 += a * w1.x; acc5 += a * w1.y; acc6 += a * w1.z; acc7 += a * w1.w;
    }

    int row = rowBase + tr;
    if (row < N_NODES) {
        float4* op = (float4*)(C + (size_t)row * F + tc);
        op[0] = make_float4(acc0, acc1, acc2, acc3);
        op[1] = make_float4(acc4, acc5, acc6, acc7);
    }
}

// ---------------- fused gather aggregation, F=256 ----------------
// MODE 0: out = agg
// MODE 1: out = relu(agg)
// MODE 2: out = relu(relu(agg) + hc)
// agg = bias + H[n]*dinv[n]^2 + sum_e w_e * H[src_e]

template <int MODE>
__global__ __launch_bounds__(256) void k_gather256(const float* __restrict__ H,
                                                   const float* __restrict__ bias,
                                                   const float* __restrict__ dinv,
                                                   const int* __restrict__ rowptr,
                                                   const int* __restrict__ csr_src,
                                                   const float* __restrict__ csr_w,
                                                   const float* __restrict__ hc,
                                                   float* __restrict__ OUT) {
    int gid = blockIdx.x * 256 + threadIdx.x;
    int n = gid >> 6;
    int lane = gid & 63;
    if (n >= N_NODES) return;
    int c = lane * 4;

    float di = dinv[n];
    float s = di * di;
    const float4 h = *(const float4*)(H + (size_t)n * F + c);
    const float4 b = *(const float4*)(bias + c);
    float ax = b.x + h.x * s;
    float ay = b.y + h.y * s;
    float az = b.z + h.z * s;
    float aw = b.w + h.w * s;

    int i = rowptr[n];
    const int end = rowptr[n + 1];
    // 2-deep unroll for load overlap
    for (; i + 1 < end; i += 2) {
        int s0 = csr_src[i];
        int s1 = csr_src[i + 1];
        float w0 = csr_w[i];
        float w1 = csr_w[i + 1];
        const float4 v0 = *(const float4*)(H + (size_t)s0 * F + c);
        const float4 v1 = *(const float4*)(H + (size_t)s1 * F + c);
        ax += w0 * v0.x + w1 * v1.x;
        ay += w0 * v0.y + w1 * v1.y;
        az += w0 * v0.z + w1 * v1.z;
        aw += w0 * v0.w + w1 * v1.w;
    }
    if (i < end) {
        int s0 = csr_src[i];
        float w0 = csr_w[i];
        const float4 v0 = *(const float4*)(H + (size_t)s0 * F + c);
        ax += w0 * v0.x; ay += w0 * v0.y; az += w0 * v0.z; aw += w0 * v0.w;
    }

    float4 o;
    if (MODE == 0) {
        o = make_float4(ax, ay, az, aw);
    } else if (MODE == 1) {
        o = make_float4(fmaxf(ax, 0.f), fmaxf(ay, 0.f), fmaxf(az, 0.f), fmaxf(aw, 0.f));
    } else {
        const float4 hcv = *(const float4*)(hc + (size_t)n * F + c);
        o.x = fmaxf(fmaxf(ax, 0.f) + hcv.x, 0.f);
        o.y = fmaxf(fmaxf(ay, 0.f) + hcv.y, 0.f);
        o.z = fmaxf(fmaxf(az, 0.f) + hcv.z, 0.f);
        o.w = fmaxf(fmaxf(aw, 0.f) + hcv.w, 0.f);
    }
    *(float4*)(OUT + (size_t)n * F + c) = o;
}

// ---------------- layer 4: GEMM 256 -> 16 ----------------

__global__ __launch_bounds__(256) void k_gemm16(const float* __restrict__ A,
                                                const float* __restrict__ W4,
                                                float* __restrict__ C) {
    __shared__ float Ws[256][16];
    const int t = threadIdx.x;
    {
        const float4* wp = (const float4*)(W4 + (size_t)t * 16);
        float4 a = wp[0], b = wp[1], c = wp[2], d = wp[3];
        float4* sp = (float4*)&Ws[t][0];
        sp[0] = a; sp[1] = b; sp[2] = c; sp[3] = d;
    }
    __syncthreads();
    int row = blockIdx.x * 256 + t;
    if (row >= N_NODES) return;
    const float4* ap = (const float4*)(A + (size_t)row * F);
    float acc[16];
#pragma unroll
    for (int c = 0; c < 16; ++c) acc[c] = 0.f;
    for (int k4 = 0; k4 < 64; ++k4) {
        float4 a = ap[k4];
        float av[4] = {a.x, a.y, a.z, a.w};
#pragma unroll
        for (int j = 0; j < 4; ++j) {
            const float4* wr = (const float4*)&Ws[k4 * 4 + j][0];
            float4 w0 = wr[0], w1 = wr[1], w2 = wr[2], w3 = wr[3];
            acc[0]  += av[j] * w0.x; acc[1]  += av[j] * w0.y;
            acc[2]  += av[j] * w0.z; acc[3]  += av[j] * w0.w;
            acc[4]  += av[j] * w1.x; acc[5]  += av[j] * w1.y;
            acc[6]  += av[j] * w1.z; acc[7]  += av[j] * w1.w;
            acc[8]  += av[j] * w2.x; acc[9]  += av[j] * w2.y;
            acc[10] += av[j] * w2.z; acc[11] += av[j] * w2.w;
            acc[12] += av[j] * w3.x; acc[13] += av[j] * w3.y;
            acc[14] += av[j] * w3.z; acc[15] += av[j] * w3.w;
        }
    }
    float4* op = (float4*)(C + (size_t)row * 16);
    op[0] = make_float4(acc[0], acc[1], acc[2], acc[3]);
    op[1] = make_float4(acc[4], acc[5], acc[6], acc[7]);
    op[2] = make_float4(acc[8], acc[9], acc[10], acc[11]);
    op[3] = make_float4(acc[12], acc[13], acc[14], acc[15]);
}

// gather for F=16: one thread per (node, float4)
__global__ __launch_bounds__(256) void k_gather16(const float* __restrict__ H16,
                                                  const float* __restrict__ bias,
                                                  const float* __restrict__ dinv,
                                                  const int* __restrict__ rowptr,
                                                  const int* __restrict__ csr_src,
                                                  const float* __restrict__ csr_w,
                                                  float* __restrict__ OUT) {
    int gid = blockIdx.x * 256 + threadIdx.x;
    int n = gid >> 2;
    int q = (gid & 3) * 4;
    if (n >= N_NODES) return;

    float di = dinv[n];
    float s = di * di;
    const float4 h = *(const float4*)(H16 + (size_t)n * 16 + q);
    const float4 b = *(const float4*)(bias + q);
    float ax = b.x + h.x * s, ay = b.y + h.y * s, az = b.z + h.z * s, aw = b.w + h.w * s;

    const int end = rowptr[n + 1];
    for (int i = rowptr[n]; i < end; ++i) {
        int s0 = csr_src[i];
        float w0 = csr_w[i];
        const float4 v = *(const float4*)(H16 + (size_t)s0 * 16 + q);
        ax += w0 * v.x; ay += w0 * v.y; az += w0 * v.z; aw += w0 * v.w;
    }
    *(float4*)(OUT + (size_t)n * 16 + q) = make_float4(ax, ay, az, aw);
}

// ---------------- mean pool ----------------

__global__ __launch_bounds__(256) void k_pool_zero(float* __restrict__ pool,
                                                   float* __restrict__ cnt) {
    int i = blockIdx.x * 256 + threadIdx.x;
    if (i < NGRAPH * NCLS) pool[i] = 0.f;
    if (i < NGRAPH) cnt[i] = 0.f;
}

__global__ __launch_bounds__(256) void k_pool(const float* __restrict__ H4,
                                              const int* __restrict__ batch,
                                              float* __restrict__ pool,
                                              float* __restrict__ cnt) {
    __shared__ float ps[NGRAPH][NCLS];
    __shared__ float pc[NGRAPH];
    for (int i = threadIdx.x; i < NGRAPH * NCLS; i += 256) ((float*)ps)[i] = 0.f;
    if (threadIdx.x < NGRAPH) pc[threadIdx.x] = 0.f;
    __syncthreads();
    int n = blockIdx.x * 256 + threadIdx.x;
    if (n < N_NODES) {
        int g = batch[n];
        const float4* hp = (const float4*)(H4 + (size_t)n * 16);
        float4 a = hp[0], b = hp[1], c = hp[2], d = hp[3];
        atomicAdd(&ps[g][0],  a.x); atomicAdd(&ps[g][1],  a.y);
        atomicAdd(&ps[g][2],  a.z); atomicAdd(&ps[g][3],  a.w);
        atomicAdd(&ps[g][4],  b.x); atomicAdd(&ps[g][5],  b.y);
        atomicAdd(&ps[g][6],  b.z); atomicAdd(&ps[g][7],  b.w);
        atomicAdd(&ps[g][8],  c.x); atomicAdd(&ps[g][9],  c.y);
        atomicAdd(&ps[g][10], c.z); atomicAdd(&ps[g][11], c.w);
        atomicAdd(&ps[g][12], d.x); atomicAdd(&ps[g][13], d.y);
        atomicAdd(&ps[g][14], d.z); atomicAdd(&ps[g][15], d.w);
        atomicAdd(&pc[g], 1.f);
    }
    __syncthreads();
    for (int i = threadIdx.x; i < NGRAPH * NCLS; i += 256)
        unsafeAtomicAdd(&pool[i], ((float*)ps)[i]);
    if (threadIdx.x < NGRAPH) unsafeAtomicAdd(&cnt[threadIdx.x], pc[threadIdx.x]);
}

__global__ __launch_bounds__(256) void k_final(const float* __restrict__ pool,
                                               const float* __restrict__ cnt,
                                               float* __restrict__ out) {
    int i = blockIdx.x * 256 + threadIdx.x;
    if (i < NGRAPH * NCLS) out[i] = pool[i] / fmaxf(cnt[i >> 4], 1.f);
}

// ---------------- host ----------------

extern "C" void kernel_launch(void* const* d_in, const int* in_sizes, int n_in,
                              void* d_out, int out_size, void* d_ws, size_t ws_size,
                              hipStream_t stream) {
    const float* x   = (const float*)d_in[0];
    const int*   ei  = (const int*)d_in[1];
    const int*   bvec= (const int*)d_in[2];
    const float* W1  = (const float*)d_in[3];
    const float* b1  = (const float*)d_in[4];
    const float* W2  = (const float*)d_in[5];
    const float* b2  = (const float*)d_in[6];
    const float* W3  = (const float*)d_in[7];
    const float* b3  = (const float*)d_in[8];
    const float* W4  = (const float*)d_in[9];
    const float* b4  = (const float*)d_in[10];
    float* out = (float*)d_out;

    const int* src = ei;
    const int* dst = ei + N_EDGES;

    const size_t NF = (size_t)N_NODES * F;
    float* ws = (float*)d_ws;
    float* P0 = ws;
    float* P1 = ws + NF;
    float* P2 = ws + 2 * NF;
    float* aux = ws + 3 * NF;
    int*   ecnt   = (int*)aux;                     // N
    float* dinv   = aux + N_NODES;                 // N
    int*   rowptr = (int*)(aux + 2 * N_NODES);     // N+1
    int*   cursor = (int*)(aux + 3 * N_NODES + 64);// N
    int*   blkSum = (int*)(aux + 4 * N_NODES + 64);// 256
    int*   blkOff = blkSum + 256;                  // 256
    int*   csr_src= blkOff + 256;                  // E
    float* csr_w  = (float*)(csr_src + N_EDGES);   // E
    float* pool   = csr_w + N_EDGES;
    float* cnt    = pool + NGRAPH * NCLS;

    const int BN = NBLK_N;                       // 196
    const int BE = (N_EDGES + 255) / 256;        // 3125
    const int BG = (N_NODES * 64 + 255) / 256;   // 12500 (wave/node)
    const dim3 GG((N_NODES + 31) / 32, 4);

    // ---- CSR build + norms
    k_zero_int<<<BN, 256, 0, stream>>>(ecnt, N_NODES);
    k_count<<<BE, 256, 0, stream>>>(dst, ecnt);
    k_dinv<<<BN, 256, 0, stream>>>(ecnt, dinv);
    k_scan_block<<<BN, 256, 0, stream>>>(ecnt, rowptr, blkSum);
    k_scan_tops<<<1, 256, 0, stream>>>(blkSum, blkOff);
    k_scan_add<<<BN, 256, 0, stream>>>(rowptr, blkOff, cursor);
    k_fill_csr<<<BE, 256, 0, stream>>>(src, dst, dinv, cursor, csr_src, csr_w);

    // ---- layer 1: P0 = x@W1; P1 = relu(agg(P0))
    k_gemm256<<<GG, 256, 0, stream>>>(x, W1, P0);
    k_gather256<1><<<BG, 256, 0, stream>>>(P0, b1, dinv, rowptr, csr_src, csr_w, nullptr, P1);

    // ---- layer 2: P0 = P1@W2; P2 = relu(relu(agg(P0)) + P1)
    k_gemm256<<<GG, 256, 0, stream>>>(P1, W2, P0);
    k_gather256<2><<<BG, 256, 0, stream>>>(P0, b2, dinv, rowptr, csr_src, csr_w, P1, P2);

    // ---- layer 3: P0 = P2@W3; P1 = relu(relu(agg(P0)) + P2)
    k_gemm256<<<GG, 256, 0, stream>>>(P2, W3, P0);
    k_gather256<2><<<BG, 256, 0, stream>>>(P0, b3, dinv, rowptr, csr_src, csr_w, P2, P1);

    // ---- layer 4: P0[:,0:16] = P1@W4; P2 = agg16(P0)
    k_gemm16<<<BN, 256, 0, stream>>>(P1, W4, P0);
    k_gather16<<<(N_NODES * 4 + 255) / 256, 256, 0, stream>>>(P0, b4, dinv, rowptr, csr_src, csr_w, P2);

    // ---- mean pool
    k_pool_zero<<<5, 256, 0, stream>>>(pool, cnt);
    k_pool<<<BN, 256, 0, stream>>>(P2, bvec, pool, cnt);
    k_final<<<4, 256, 0, stream>>>(pool, cnt, out);
}

// Round 3
// 596.503 us; speedup vs baseline: 15.8348x; 2.7238x over previous
//
#include <hip/hip_runtime.h>
#include <hip/hip_bf16.h>

#define N_NODES 50000
#define N_EDGES 800000
#define F 256
#define NGRAPH 64
#define NCLS 16
#define NBLK_N 196   // ceil(50000/256)

typedef short short8 __attribute__((ext_vector_type(8)));
typedef float f32x4 __attribute__((ext_vector_type(4)));

__device__ __forceinline__ float bf2f(ushort u) {
    unsigned v = ((unsigned)u) << 16;
    return __uint_as_float(v);
}
__device__ __forceinline__ ushort f2bf(float f) {
    __hip_bfloat16 b = __float2bfloat16(f);   // RNE
    return *reinterpret_cast<ushort*>(&b);
}

// ---------------- CSR build ----------------

__global__ __launch_bounds__(256) void k_zero_int(int* __restrict__ p, int n) {
    int i = blockIdx.x * 256 + threadIdx.x;
    if (i < n) p[i] = 0;
}

__global__ __launch_bounds__(256) void k_count(const int* __restrict__ dst,
                                               int* __restrict__ ecnt) {
    int e = blockIdx.x * 256 + threadIdx.x;
    if (e < N_EDGES) atomicAdd(&ecnt[dst[e]], 1);
}

__global__ __launch_bounds__(256) void k_dinv(const int* __restrict__ ecnt,
                                              float* __restrict__ dinv) {
    int n = blockIdx.x * 256 + threadIdx.x;
    if (n < N_NODES) dinv[n] = rsqrtf((float)(ecnt[n] + 1));  // +1 self-loop
}

__global__ __launch_bounds__(256) void k_scan_block(const int* __restrict__ ecnt,
                                                    int* __restrict__ rowptr,
                                                    int* __restrict__ blkSum) {
    __shared__ int sh[256];
    int i = blockIdx.x * 256 + threadIdx.x;
    int v = (i < N_NODES) ? ecnt[i] : 0;
    sh[threadIdx.x] = v;
    __syncthreads();
#pragma unroll
    for (int off = 1; off < 256; off <<= 1) {
        int t = (threadIdx.x >= off) ? sh[threadIdx.x - off] : 0;
        __syncthreads();
        sh[threadIdx.x] += t;
        __syncthreads();
    }
    if (i < N_NODES) rowptr[i] = sh[threadIdx.x] - v;
    if (threadIdx.x == 255) blkSum[blockIdx.x] = sh[255];
}

__global__ __launch_bounds__(256) void k_scan_tops(int* __restrict__ blkSum,
                                                   int* __restrict__ blkOff) {
    __shared__ int sh[256];
    int v = (threadIdx.x < NBLK_N) ? blkSum[threadIdx.x] : 0;
    sh[threadIdx.x] = v;
    __syncthreads();
#pragma unroll
    for (int off = 1; off < 256; off <<= 1) {
        int t = (threadIdx.x >= off) ? sh[threadIdx.x - off] : 0;
        __syncthreads();
        sh[threadIdx.x] += t;
        __syncthreads();
    }
    if (threadIdx.x < NBLK_N) blkOff[threadIdx.x] = sh[threadIdx.x] - v;
}

__global__ __launch_bounds__(256) void k_scan_add(int* __restrict__ rowptr,
                                                  const int* __restrict__ blkOff,
                                                  int* __restrict__ cursor) {
    int i = blockIdx.x * 256 + threadIdx.x;
    if (i < N_NODES) {
        int r = rowptr[i] + blkOff[blockIdx.x];
        rowptr[i] = r;
        cursor[i] = r;
    }
    if (i == 0) rowptr[N_NODES] = N_EDGES;
}

__global__ __launch_bounds__(256) void k_fill_csr(const int* __restrict__ src,
                                                  const int* __restrict__ dst,
                                                  const float* __restrict__ dinv,
                                                  int* __restrict__ cursor,
                                                  int* __restrict__ csr_src,
                                                  float* __restrict__ csr_w) {
    int e = blockIdx.x * 256 + threadIdx.x;
    if (e >= N_EDGES) return;
    int s = src[e];
    int d = dst[e];
    int p = atomicAdd(&cursor[d], 1);
    csr_src[p] = s;
    csr_w[p] = dinv[s] * dinv[d];
}

// ---------------- casts / packs ----------------

// f32 -> bf16, 8 elems/thread
__global__ __launch_bounds__(256) void k_cast_bf16(const float* __restrict__ in,
                                                   ushort* __restrict__ out,
                                                   int n8) {
    int i = blockIdx.x * 256 + threadIdx.x;
    if (i >= n8) return;
    const float4* ip = (const float4*)(in + (size_t)i * 8);
    float4 a = ip[0], b = ip[1];
    short8 v;
    v[0] = (short)f2bf(a.x); v[1] = (short)f2bf(a.y);
    v[2] = (short)f2bf(a.z); v[3] = (short)f2bf(a.w);
    v[4] = (short)f2bf(b.x); v[5] = (short)f2bf(b.y);
    v[6] = (short)f2bf(b.z); v[7] = (short)f2bf(b.w);
    *(short8*)(out + (size_t)i * 8) = v;
}

// pack W[256][256] f32 -> fragment order bf16:
// Wp[((ctg*8+ks)*64 + lane)*8 + e] = W[ks*32 + (lane>>4)*8 + e][ctg*16 + (lane&15)]
__global__ __launch_bounds__(256) void k_wpack(const float* __restrict__ W,
                                               ushort* __restrict__ Wp) {
    int idx = blockIdx.x * 256 + threadIdx.x;
    if (idx >= 16 * 8 * 64) return;
    int lane = idx & 63;
    int ks = (idx >> 6) & 7;
    int ctg = idx >> 9;
    int kbase = ks * 32 + (lane >> 4) * 8;
    int col = ctg * 16 + (lane & 15);
    short8 v;
#pragma unroll
    for (int e = 0; e < 8; ++e)
        v[e] = (short)f2bf(W[(size_t)(kbase + e) * 256 + col]);
    *(short8*)(Wp + (size_t)idx * 8) = v;
}

// ---------------- MFMA GEMM: C[M][256] f32 = A_bf16[M][256] @ W_bf16[256][256] ----------------
// block = 256 thr (4 waves). BM=64: wave w covers all 64 rows x cols [w*64, w*64+64).

__global__ __launch_bounds__(256, 2) void k_mfma256(const ushort* __restrict__ Ab,
                                                    const ushort* __restrict__ Wp,
                                                    float* __restrict__ C) {
    const int t = threadIdx.x;
    const int wv = t >> 6;
    const int l = t & 63;
    const int m0 = blockIdx.x * 64;
    const int colbase = wv * 64;
    const int lrow = l & 15;
    const int lk = (l >> 4) * 8;

    // W fragments for this wave's 4 col-tiles, all 8 k-steps
    short8 wf[4][8];
    const short8* wp = (const short8*)Wp;
#pragma unroll
    for (int ct = 0; ct < 4; ++ct)
#pragma unroll
        for (int ks = 0; ks < 8; ++ks)
            wf[ct][ks] = wp[(size_t)(((wv * 4 + ct) * 8 + ks) * 64) + l];

#pragma unroll
    for (int msub = 0; msub < 4; ++msub) {
        int arow = m0 + msub * 16 + lrow;
        if (arow >= N_NODES) arow = N_NODES - 1;
        const ushort* ap = Ab + (size_t)arow * F + lk;
        short8 af[8];
#pragma unroll
        for (int ks = 0; ks < 8; ++ks)
            af[ks] = *(const short8*)(ap + ks * 32);

        f32x4 acc[4];
#pragma unroll
        for (int ct = 0; ct < 4; ++ct) acc[ct] = (f32x4){0.f, 0.f, 0.f, 0.f};
#pragma unroll
        for (int ks = 0; ks < 8; ++ks)
#pragma unroll
            for (int ct = 0; ct < 4; ++ct)
                acc[ct] = __builtin_amdgcn_mfma_f32_16x16x32_bf16(af[ks], wf[ct][ks], acc[ct], 0, 0, 0);

        int orow0 = m0 + msub * 16 + (l >> 4) * 4;
#pragma unroll
        for (int ct = 0; ct < 4; ++ct) {
            int ocol = colbase + ct * 16 + (l & 15);
#pragma unroll
            for (int r = 0; r < 4; ++r) {
                int orow = orow0 + r;
                if (orow < N_NODES)
                    C[(size_t)orow * F + ocol] = acc[ct][r];
            }
        }
    }
}

// ---------------- fused gather aggregation, F=256, bf16 out ----------------
// MODE 1: out = relu(agg)           MODE 2: out = relu(relu(agg) + hc)
// agg = bias + H[n]*dinv[n]^2 + sum_e w_e * H[src_e]

template <int MODE>
__global__ __launch_bounds__(256) void k_gather256(const float* __restrict__ H,
                                                   const float* __restrict__ bias,
                                                   const float* __restrict__ dinv,
                                                   const int* __restrict__ rowptr,
                                                   const int* __restrict__ csr_src,
                                                   const float* __restrict__ csr_w,
                                                   const ushort* __restrict__ hc,
                                                   ushort* __restrict__ OUT) {
    int gid = blockIdx.x * 256 + threadIdx.x;
    int n = gid >> 6;
    int lane = gid & 63;
    if (n >= N_NODES) return;
    int c = lane * 4;

    float di = dinv[n];
    float s = di * di;
    const float4 h = *(const float4*)(H + (size_t)n * F + c);
    const float4 b = *(const float4*)(bias + c);
    float ax = b.x + h.x * s;
    float ay = b.y + h.y * s;
    float az = b.z + h.z * s;
    float aw = b.w + h.w * s;

    int i = rowptr[n];
    const int end = rowptr[n + 1];
    for (; i + 1 < end; i += 2) {
        int s0 = csr_src[i];
        int s1 = csr_src[i + 1];
        float w0 = csr_w[i];
        float w1 = csr_w[i + 1];
        const float4 v0 = *(const float4*)(H + (size_t)s0 * F + c);
        const float4 v1 = *(const float4*)(H + (size_t)s1 * F + c);
        ax += w0 * v0.x + w1 * v1.x;
        ay += w0 * v0.y + w1 * v1.y;
        az += w0 * v0.z + w1 * v1.z;
        aw += w0 * v0.w + w1 * v1.w;
    }
    if (i < end) {
        int s0 = csr_src[i];
        float w0 = csr_w[i];
        const float4 v0 = *(const float4*)(H + (size_t)s0 * F + c);
        ax += w0 * v0.x; ay += w0 * v0.y; az += w0 * v0.z; aw += w0 * v0.w;
    }

    float ox, oy, oz, ow;
    if (MODE == 1) {
        ox = fmaxf(ax, 0.f); oy = fmaxf(ay, 0.f);
        oz = fmaxf(az, 0.f); ow = fmaxf(aw, 0.f);
    } else {
        const ushort4 hv = *(const ushort4*)(hc + (size_t)n * F + c);
        ox = fmaxf(fmaxf(ax, 0.f) + bf2f(hv.x), 0.f);
        oy = fmaxf(fmaxf(ay, 0.f) + bf2f(hv.y), 0.f);
        oz = fmaxf(fmaxf(az, 0.f) + bf2f(hv.z), 0.f);
        ow = fmaxf(fmaxf(aw, 0.f) + bf2f(hv.w), 0.f);
    }
    ushort4 ov;
    ov.x = f2bf(ox); ov.y = f2bf(oy); ov.z = f2bf(oz); ov.w = f2bf(ow);
    *(ushort4*)(OUT + (size_t)n * F + c) = ov;
}

// ---------------- layer 4: GEMM 256 -> 16 (bf16 A) ----------------

__global__ __launch_bounds__(256) void k_gemm16(const ushort* __restrict__ A,
                                                const float* __restrict__ W4,
                                                float* __restrict__ C) {
    __shared__ float Ws[256][16];
    const int t = threadIdx.x;
    {
        const float4* wp = (const float4*)(W4 + (size_t)t * 16);
        float4 a = wp[0], b = wp[1], c = wp[2], d = wp[3];
        float4* sp = (float4*)&Ws[t][0];
        sp[0] = a; sp[1] = b; sp[2] = c; sp[3] = d;
    }
    __syncthreads();
    int row = blockIdx.x * 256 + t;
    if (row >= N_NODES) return;
    const short8* ap = (const short8*)(A + (size_t)row * F);
    float acc[16];
#pragma unroll
    for (int c = 0; c < 16; ++c) acc[c] = 0.f;
    for (int k8 = 0; k8 < 32; ++k8) {
        short8 a8 = ap[k8];
#pragma unroll
        for (int j = 0; j < 8; ++j) {
            float av = bf2f((ushort)a8[j]);
            const float4* wr = (const float4*)&Ws[k8 * 8 + j][0];
            float4 w0 = wr[0], w1 = wr[1], w2 = wr[2], w3 = wr[3];
            acc[0]  += av * w0.x; acc[1]  += av * w0.y;
            acc[2]  += av * w0.z; acc[3]  += av * w0.w;
            acc[4]  += av * w1.x; acc[5]  += av * w1.y;
            acc[6]  += av * w1.z; acc[7]  += av * w1.w;
            acc[8]  += av * w2.x; acc[9]  += av * w2.y;
            acc[10] += av * w2.z; acc[11] += av * w2.w;
            acc[12] += av * w3.x; acc[13] += av * w3.y;
            acc[14] += av * w3.z; acc[15] += av * w3.w;
        }
    }
    float4* op = (float4*)(C + (size_t)row * 16);
    op[0] = make_float4(acc[0], acc[1], acc[2], acc[3]);
    op[1] = make_float4(acc[4], acc[5], acc[6], acc[7]);
    op[2] = make_float4(acc[8], acc[9], acc[10], acc[11]);
    op[3] = make_float4(acc[12], acc[13], acc[14], acc[15]);
}

// gather for F=16: one thread per (node, float4)
__global__ __launch_bounds__(256) void k_gather16(const float* __restrict__ H16,
                                                  const float* __restrict__ bias,
                                                  const float* __restrict__ dinv,
                                                  const int* __restrict__ rowptr,
                                                  const int* __restrict__ csr_src,
                                                  const float* __restrict__ csr_w,
                                                  float* __restrict__ OUT) {
    int gid = blockIdx.x * 256 + threadIdx.x;
    int n = gid >> 2;
    int q = (gid & 3) * 4;
    if (n >= N_NODES) return;

    float di = dinv[n];
    float s = di * di;
    const float4 h = *(const float4*)(H16 + (size_t)n * 16 + q);
    const float4 b = *(const float4*)(bias + q);
    float ax = b.x + h.x * s, ay = b.y + h.y * s, az = b.z + h.z * s, aw = b.w + h.w * s;

    const int end = rowptr[n + 1];
    for (int i = rowptr[n]; i < end; ++i) {
        int s0 = csr_src[i];
        float w0 = csr_w[i];
        const float4 v = *(const float4*)(H16 + (size_t)s0 * 16 + q);
        ax += w0 * v.x; ay += w0 * v.y; az += w0 * v.z; aw += w0 * v.w;
    }
    *(float4*)(OUT + (size_t)n * 16 + q) = make_float4(ax, ay, az, aw);
}

// ---------------- mean pool ----------------

__global__ __launch_bounds__(256) void k_pool_zero(float* __restrict__ pool,
                                                   float* __restrict__ cnt) {
    int i = blockIdx.x * 256 + threadIdx.x;
    if (i < NGRAPH * NCLS) pool[i] = 0.f;
    if (i < NGRAPH) cnt[i] = 0.f;
}

__global__ __launch_bounds__(256) void k_pool(const float* __restrict__ H4,
                                              const int* __restrict__ batch,
                                              float* __restrict__ pool,
                                              float* __restrict__ cnt) {
    __shared__ float ps[NGRAPH][NCLS];
    __shared__ float pc[NGRAPH];
    for (int i = threadIdx.x; i < NGRAPH * NCLS; i += 256) ((float*)ps)[i] = 0.f;
    if (threadIdx.x < NGRAPH) pc[threadIdx.x] = 0.f;
    __syncthreads();
    int n = blockIdx.x * 256 + threadIdx.x;
    if (n < N_NODES) {
        int g = batch[n];
        const float4* hp = (const float4*)(H4 + (size_t)n * 16);
        float4 a = hp[0], b = hp[1], c = hp[2], d = hp[3];
        atomicAdd(&ps[g][0],  a.x); atomicAdd(&ps[g][1],  a.y);
        atomicAdd(&ps[g][2],  a.z); atomicAdd(&ps[g][3],  a.w);
        atomicAdd(&ps[g][4],  b.x); atomicAdd(&ps[g][5],  b.y);
        atomicAdd(&ps[g][6],  b.z); atomicAdd(&ps[g][7],  b.w);
        atomicAdd(&ps[g][8],  c.x); atomicAdd(&ps[g][9],  c.y);
        atomicAdd(&ps[g][10], c.z); atomicAdd(&ps[g][11], c.w);
        atomicAdd(&ps[g][12], d.x); atomicAdd(&ps[g][13], d.y);
        atomicAdd(&ps[g][14], d.z); atomicAdd(&ps[g][15], d.w);
        atomicAdd(&pc[g], 1.f);
    }
    __syncthreads();
    for (int i = threadIdx.x; i < NGRAPH * NCLS; i += 256)
        unsafeAtomicAdd(&pool[i], ((float*)ps)[i]);
    if (threadIdx.x < NGRAPH) unsafeAtomicAdd(&cnt[threadIdx.x], pc[threadIdx.x]);
}

__global__ __launch_bounds__(256) void k_final(const float* __restrict__ pool,
                                               const float* __restrict__ cnt,
                                               float* __restrict__ out) {
    int i = blockIdx.x * 256 + threadIdx.x;
    if (i < NGRAPH * NCLS) out[i] = pool[i] / fmaxf(cnt[i >> 4], 1.f);
}

// ---------------- host ----------------

extern "C" void kernel_launch(void* const* d_in, const int* in_sizes, int n_in,
                              void* d_out, int out_size, void* d_ws, size_t ws_size,
                              hipStream_t stream) {
    const float* x   = (const float*)d_in[0];
    const int*   ei  = (const int*)d_in[1];
    const int*   bvec= (const int*)d_in[2];
    const float* W1  = (const float*)d_in[3];
    const float* b1  = (const float*)d_in[4];
    const float* W2  = (const float*)d_in[5];
    const float* b2  = (const float*)d_in[6];
    const float* W3  = (const float*)d_in[7];
    const float* b3  = (const float*)d_in[8];
    const float* W4  = (const float*)d_in[9];
    const float* b4  = (const float*)d_in[10];
    float* out = (float*)d_out;

    const int* src = ei;
    const int* dst = ei + N_EDGES;

    const size_t NF = (size_t)N_NODES * F;     // 12.8M
    float* ws = (float*)d_ws;
    float*  P0 = ws;                            // NF f32
    ushort* B1 = (ushort*)(ws + NF);            // NF bf16
    ushort* B2 = (ushort*)(ws + NF + NF / 2);   // NF bf16
    float*  H4 = ws + 2 * NF;                   // 800000 f32
    float* aux = ws + 2 * NF + 800000;
    int*   ecnt   = (int*)aux;                      // N
    float* dinv   = aux + N_NODES;                  // N
    int*   rowptr = (int*)(aux + 2 * N_NODES);      // N+1 (+pad)
    int*   cursor = (int*)(aux + 3 * N_NODES + 64); // N
    int*   blkSum = (int*)(aux + 4 * N_NODES + 64); // 256
    int*   blkOff = blkSum + 256;                   // 256
    int*   csr_src= blkOff + 256;                   // E
    float* csr_w  = (float*)(csr_src + N_EDGES);    // E
    float* pool   = csr_w + N_EDGES;                // 1024
    float* cnt    = pool + NGRAPH * NCLS;           // 64
    ushort* Wp1   = (ushort*)(cnt + NGRAPH);        // 65536 each
    ushort* Wp2   = Wp1 + 65536;
    ushort* Wp3   = Wp2 + 65536;

    const int BN = NBLK_N;                       // 196
    const int BE = (N_EDGES + 255) / 256;        // 3125
    const int BG = (N_NODES * 64 + 255) / 256;   // 12500 (wave/node)
    const int BM = (N_NODES + 63) / 64;          // 782 MFMA blocks
    const int BC = (int)((NF / 8 + 255) / 256);  // cast blocks

    // ---- casts & weight packs
    k_cast_bf16<<<BC, 256, 0, stream>>>(x, B1, (int)(NF / 8));
    k_wpack<<<32, 256, 0, stream>>>(W1, Wp1);
    k_wpack<<<32, 256, 0, stream>>>(W2, Wp2);
    k_wpack<<<32, 256, 0, stream>>>(W3, Wp3);

    // ---- CSR build + norms
    k_zero_int<<<BN, 256, 0, stream>>>(ecnt, N_NODES);
    k_count<<<BE, 256, 0, stream>>>(dst, ecnt);
    k_dinv<<<BN, 256, 0, stream>>>(ecnt, dinv);
    k_scan_block<<<BN, 256, 0, stream>>>(ecnt, rowptr, blkSum);
    k_scan_tops<<<1, 256, 0, stream>>>(blkSum, blkOff);
    k_scan_add<<<BN, 256, 0, stream>>>(rowptr, blkOff, cursor);
    k_fill_csr<<<BE, 256, 0, stream>>>(src, dst, dinv, cursor, csr_src, csr_w);

    // ---- layer 1: P0 = B1@W1; B2 = relu(agg(P0))
    k_mfma256<<<BM, 256, 0, stream>>>(B1, Wp1, P0);
    k_gather256<1><<<BG, 256, 0, stream>>>(P0, b1, dinv, rowptr, csr_src, csr_w, nullptr, B2);

    // ---- layer 2: P0 = B2@W2; B1 = relu(relu(agg(P0)) + B2)
    k_mfma256<<<BM, 256, 0, stream>>>(B2, Wp2, P0);
    k_gather256<2><<<BG, 256, 0, stream>>>(P0, b2, dinv, rowptr, csr_src, csr_w, B2, B1);

    // ---- layer 3: P0 = B1@W3; B2 = relu(relu(agg(P0)) + B1)
    k_mfma256<<<BM, 256, 0, stream>>>(B1, Wp3, P0);
    k_gather256<2><<<BG, 256, 0, stream>>>(P0, b3, dinv, rowptr, csr_src, csr_w, B1, B2);

    // ---- layer 4: P0[:,0:16] = B2@W4; H4 = agg16(P0)
    k_gemm16<<<BN, 256, 0, stream>>>(B2, W4, P0);
    k_gather16<<<(N_NODES * 4 + 255) / 256, 256, 0, stream>>>(P0, b4, dinv, rowptr, csr_src, csr_w, H4);

    // ---- mean pool
    k_pool_zero<<<5, 256, 0, stream>>>(pool, cnt);
    k_pool<<<BN, 256, 0, stream>>>(H4, bvec, pool, cnt);
    k_final<<<4, 256, 0, stream>>>(pool, cnt, out);
}

// Round 4
// 422.833 us; speedup vs baseline: 22.3386x; 1.4107x over previous
//
#include <hip/hip_runtime.h>
#include <hip/hip_bf16.h>

#define N_NODES 50000
#define N_EDGES 800000
#define F 256
#define NGRAPH 64
#define NCLS 16
#define NBLK_N 196   // ceil(50000/256)

typedef short short8 __attribute__((ext_vector_type(8)));
typedef float f32x4 __attribute__((ext_vector_type(4)));

__device__ __forceinline__ float bf2f(ushort u) {
    unsigned v = ((unsigned)u) << 16;
    return __uint_as_float(v);
}
__device__ __forceinline__ ushort f2bf(float f) {
    __hip_bfloat16 b = __float2bfloat16(f);   // RNE
    return *reinterpret_cast<ushort*>(&b);
}

// ---------------- CSR build ----------------

__global__ __launch_bounds__(256) void k_zero_int(int* __restrict__ p, int n) {
    int i = blockIdx.x * 256 + threadIdx.x;
    if (i < n) p[i] = 0;
}

__global__ __launch_bounds__(256) void k_count(const int* __restrict__ dst,
                                               int* __restrict__ ecnt) {
    int e = blockIdx.x * 256 + threadIdx.x;
    if (e < N_EDGES) atomicAdd(&ecnt[dst[e]], 1);
}

__global__ __launch_bounds__(256) void k_dinv(const int* __restrict__ ecnt,
                                              float* __restrict__ dinv) {
    int n = blockIdx.x * 256 + threadIdx.x;
    if (n < N_NODES) dinv[n] = rsqrtf((float)(ecnt[n] + 1));  // +1 self-loop
}

__global__ __launch_bounds__(256) void k_scan_block(const int* __restrict__ ecnt,
                                                    int* __restrict__ rowptr,
                                                    int* __restrict__ blkSum) {
    __shared__ int sh[256];
    int i = blockIdx.x * 256 + threadIdx.x;
    int v = (i < N_NODES) ? ecnt[i] : 0;
    sh[threadIdx.x] = v;
    __syncthreads();
#pragma unroll
    for (int off = 1; off < 256; off <<= 1) {
        int t = (threadIdx.x >= off) ? sh[threadIdx.x - off] : 0;
        __syncthreads();
        sh[threadIdx.x] += t;
        __syncthreads();
    }
    if (i < N_NODES) rowptr[i] = sh[threadIdx.x] - v;
    if (threadIdx.x == 255) blkSum[blockIdx.x] = sh[255];
}

__global__ __launch_bounds__(256) void k_scan_tops(int* __restrict__ blkSum,
                                                   int* __restrict__ blkOff) {
    __shared__ int sh[256];
    int v = (threadIdx.x < NBLK_N) ? blkSum[threadIdx.x] : 0;
    sh[threadIdx.x] = v;
    __syncthreads();
#pragma unroll
    for (int off = 1; off < 256; off <<= 1) {
        int t = (threadIdx.x >= off) ? sh[threadIdx.x - off] : 0;
        __syncthreads();
        sh[threadIdx.x] += t;
        __syncthreads();
    }
    if (threadIdx.x < NBLK_N) blkOff[threadIdx.x] = sh[threadIdx.x] - v;
}

__global__ __launch_bounds__(256) void k_scan_add(int* __restrict__ rowptr,
                                                  const int* __restrict__ blkOff,
                                                  int* __restrict__ cursor) {
    int i = blockIdx.x * 256 + threadIdx.x;
    if (i < N_NODES) {
        int r = rowptr[i] + blkOff[blockIdx.x];
        rowptr[i] = r;
        cursor[i] = r;
    }
    if (i == 0) rowptr[N_NODES] = N_EDGES;
}

__global__ __launch_bounds__(256) void k_fill_csr(const int* __restrict__ src,
                                                  const int* __restrict__ dst,
                                                  const float* __restrict__ dinv,
                                                  int* __restrict__ cursor,
                                                  int* __restrict__ csr_src,
                                                  float* __restrict__ csr_w) {
    int e = blockIdx.x * 256 + threadIdx.x;
    if (e >= N_EDGES) return;
    int s = src[e];
    int d = dst[e];
    int p = atomicAdd(&cursor[d], 1);
    csr_src[p] = s;
    csr_w[p] = dinv[s] * dinv[d];
}

// ---------------- casts / packs ----------------

__global__ __launch_bounds__(256) void k_cast_bf16(const float* __restrict__ in,
                                                   ushort* __restrict__ out,
                                                   int n8) {
    int i = blockIdx.x * 256 + threadIdx.x;
    if (i >= n8) return;
    const float4* ip = (const float4*)(in + (size_t)i * 8);
    float4 a = ip[0], b = ip[1];
    short8 v;
    v[0] = (short)f2bf(a.x); v[1] = (short)f2bf(a.y);
    v[2] = (short)f2bf(a.z); v[3] = (short)f2bf(a.w);
    v[4] = (short)f2bf(b.x); v[5] = (short)f2bf(b.y);
    v[6] = (short)f2bf(b.z); v[7] = (short)f2bf(b.w);
    *(short8*)(out + (size_t)i * 8) = v;
}

// pack W[256][256] f32 -> fragment order bf16
__global__ __launch_bounds__(256) void k_wpack(const float* __restrict__ W,
                                               ushort* __restrict__ Wp) {
    int idx = blockIdx.x * 256 + threadIdx.x;
    if (idx >= 16 * 8 * 64) return;
    int lane = idx & 63;
    int ks = (idx >> 6) & 7;
    int ctg = idx >> 9;
    int kbase = ks * 32 + (lane >> 4) * 8;
    int col = ctg * 16 + (lane & 15);
    short8 v;
#pragma unroll
    for (int e = 0; e < 8; ++e)
        v[e] = (short)f2bf(W[(size_t)(kbase + e) * 256 + col]);
    *(short8*)(Wp + (size_t)idx * 8) = v;
}

// ---------------- MFMA GEMM: C_bf16[M][256] = A_bf16[M][256] @ W_bf16[256][256] ----------------

__global__ __launch_bounds__(256, 2) void k_mfma256(const ushort* __restrict__ Ab,
                                                    const ushort* __restrict__ Wp,
                                                    ushort* __restrict__ C) {
    const int t = threadIdx.x;
    const int wv = t >> 6;
    const int l = t & 63;
    const int m0 = blockIdx.x * 64;
    const int colbase = wv * 64;
    const int lrow = l & 15;
    const int lk = (l >> 4) * 8;

    short8 wf[4][8];
    const short8* wp = (const short8*)Wp;
#pragma unroll
    for (int ct = 0; ct < 4; ++ct)
#pragma unroll
        for (int ks = 0; ks < 8; ++ks)
            wf[ct][ks] = wp[(size_t)(((wv * 4 + ct) * 8 + ks) * 64) + l];

#pragma unroll
    for (int msub = 0; msub < 4; ++msub) {
        int arow = m0 + msub * 16 + lrow;
        if (arow >= N_NODES) arow = N_NODES - 1;
        const ushort* ap = Ab + (size_t)arow * F + lk;
        short8 af[8];
#pragma unroll
        for (int ks = 0; ks < 8; ++ks)
            af[ks] = *(const short8*)(ap + ks * 32);

        f32x4 acc[4];
#pragma unroll
        for (int ct = 0; ct < 4; ++ct) acc[ct] = (f32x4){0.f, 0.f, 0.f, 0.f};
#pragma unroll
        for (int ks = 0; ks < 8; ++ks)
#pragma unroll
            for (int ct = 0; ct < 4; ++ct)
                acc[ct] = __builtin_amdgcn_mfma_f32_16x16x32_bf16(af[ks], wf[ct][ks], acc[ct], 0, 0, 0);

        int orow0 = m0 + msub * 16 + (l >> 4) * 4;
#pragma unroll
        for (int ct = 0; ct < 4; ++ct) {
            int ocol = colbase + ct * 16 + (l & 15);
#pragma unroll
            for (int r = 0; r < 4; ++r) {
                int orow = orow0 + r;
                if (orow < N_NODES)
                    C[(size_t)orow * F + ocol] = f2bf(acc[ct][r]);
            }
        }
    }
}

// ---------------- fused gather aggregation, F=256, bf16 in/out ----------------
// MODE 1: out = relu(agg)           MODE 2: out = relu(relu(agg) + hc)
// agg = bias + H[n]*dinv[n]^2 + sum_e w_e * H[src_e]

template <int MODE>
__global__ __launch_bounds__(256) void k_gather256(const ushort* __restrict__ H,
                                                   const float* __restrict__ bias,
                                                   const float* __restrict__ dinv,
                                                   const int* __restrict__ rowptr,
                                                   const int* __restrict__ csr_src,
                                                   const float* __restrict__ csr_w,
                                                   const ushort* __restrict__ hc,
                                                   ushort* __restrict__ OUT) {
    int gid = blockIdx.x * 256 + threadIdx.x;
    int n = gid >> 6;
    int lane = gid & 63;
    if (n >= N_NODES) return;
    int c = lane * 4;

    float di = dinv[n];
    float s = di * di;
    const ushort4 h = *(const ushort4*)(H + (size_t)n * F + c);
    const float4 b = *(const float4*)(bias + c);
    float ax = b.x + bf2f(h.x) * s;
    float ay = b.y + bf2f(h.y) * s;
    float az = b.z + bf2f(h.z) * s;
    float aw = b.w + bf2f(h.w) * s;

    int i = rowptr[n];
    const int end = rowptr[n + 1];
    for (; i + 3 < end; i += 4) {
        int s0 = csr_src[i], s1 = csr_src[i + 1], s2 = csr_src[i + 2], s3 = csr_src[i + 3];
        float w0 = csr_w[i], w1 = csr_w[i + 1], w2 = csr_w[i + 2], w3 = csr_w[i + 3];
        const ushort4 v0 = *(const ushort4*)(H + (size_t)s0 * F + c);
        const ushort4 v1 = *(const ushort4*)(H + (size_t)s1 * F + c);
        const ushort4 v2 = *(const ushort4*)(H + (size_t)s2 * F + c);
        const ushort4 v3 = *(const ushort4*)(H + (size_t)s3 * F + c);
        ax += w0 * bf2f(v0.x) + w1 * bf2f(v1.x) + w2 * bf2f(v2.x) + w3 * bf2f(v3.x);
        ay += w0 * bf2f(v0.y) + w1 * bf2f(v1.y) + w2 * bf2f(v2.y) + w3 * bf2f(v3.y);
        az += w0 * bf2f(v0.z) + w1 * bf2f(v1.z) + w2 * bf2f(v2.z) + w3 * bf2f(v3.z);
        aw += w0 * bf2f(v0.w) + w1 * bf2f(v1.w) + w2 * bf2f(v2.w) + w3 * bf2f(v3.w);
    }
    for (; i < end; ++i) {
        int s0 = csr_src[i];
        float w0 = csr_w[i];
        const ushort4 v0 = *(const ushort4*)(H + (size_t)s0 * F + c);
        ax += w0 * bf2f(v0.x); ay += w0 * bf2f(v0.y);
        az += w0 * bf2f(v0.z); aw += w0 * bf2f(v0.w);
    }

    float ox, oy, oz, ow;
    if (MODE == 1) {
        ox = fmaxf(ax, 0.f); oy = fmaxf(ay, 0.f);
        oz = fmaxf(az, 0.f); ow = fmaxf(aw, 0.f);
    } else {
        const ushort4 hv = *(const ushort4*)(hc + (size_t)n * F + c);
        ox = fmaxf(fmaxf(ax, 0.f) + bf2f(hv.x), 0.f);
        oy = fmaxf(fmaxf(ay, 0.f) + bf2f(hv.y), 0.f);
        oz = fmaxf(fmaxf(az, 0.f) + bf2f(hv.z), 0.f);
        ow = fmaxf(fmaxf(aw, 0.f) + bf2f(hv.w), 0.f);
    }
    ushort4 ov;
    ov.x = f2bf(ox); ov.y = f2bf(oy); ov.z = f2bf(oz); ov.w = f2bf(ow);
    *(ushort4*)(OUT + (size_t)n * F + c) = ov;
}

// ---------------- layer 4: GEMM 256 -> 16 (bf16 A) ----------------

__global__ __launch_bounds__(256) void k_gemm16(const ushort* __restrict__ A,
                                                const float* __restrict__ W4,
                                                float* __restrict__ C) {
    __shared__ float Ws[256][16];
    const int t = threadIdx.x;
    {
        const float4* wp = (const float4*)(W4 + (size_t)t * 16);
        float4 a = wp[0], b = wp[1], c = wp[2], d = wp[3];
        float4* sp = (float4*)&Ws[t][0];
        sp[0] = a; sp[1] = b; sp[2] = c; sp[3] = d;
    }
    __syncthreads();
    int row = blockIdx.x * 256 + t;
    if (row >= N_NODES) return;
    const short8* ap = (const short8*)(A + (size_t)row * F);
    float acc[16];
#pragma unroll
    for (int c = 0; c < 16; ++c) acc[c] = 0.f;
    for (int k8 = 0; k8 < 32; ++k8) {
        short8 a8 = ap[k8];
#pragma unroll
        for (int j = 0; j < 8; ++j) {
            float av = bf2f((ushort)a8[j]);
            const float4* wr = (const float4*)&Ws[k8 * 8 + j][0];
            float4 w0 = wr[0], w1 = wr[1], w2 = wr[2], w3 = wr[3];
            acc[0]  += av * w0.x; acc[1]  += av * w0.y;
            acc[2]  += av * w0.z; acc[3]  += av * w0.w;
            acc[4]  += av * w1.x; acc[5]  += av * w1.y;
            acc[6]  += av * w1.z; acc[7]  += av * w1.w;
            acc[8]  += av * w2.x; acc[9]  += av * w2.y;
            acc[10] += av * w2.z; acc[11] += av * w2.w;
            acc[12] += av * w3.x; acc[13] += av * w3.y;
            acc[14] += av * w3.z; acc[15] += av * w3.w;
        }
    }
    float4* op = (float4*)(C + (size_t)row * 16);
    op[0] = make_float4(acc[0], acc[1], acc[2], acc[3]);
    op[1] = make_float4(acc[4], acc[5], acc[6], acc[7]);
    op[2] = make_float4(acc[8], acc[9], acc[10], acc[11]);
    op[3] = make_float4(acc[12], acc[13], acc[14], acc[15]);
}

__global__ __launch_bounds__(256) void k_gather16(const float* __restrict__ H16,
                                                  const float* __restrict__ bias,
                                                  const float* __restrict__ dinv,
                                                  const int* __restrict__ rowptr,
                                                  const int* __restrict__ csr_src,
                                                  const float* __restrict__ csr_w,
                                                  float* __restrict__ OUT) {
    int gid = blockIdx.x * 256 + threadIdx.x;
    int n = gid >> 2;
    int q = (gid & 3) * 4;
    if (n >= N_NODES) return;

    float di = dinv[n];
    float s = di * di;
    const float4 h = *(const float4*)(H16 + (size_t)n * 16 + q);
    const float4 b = *(const float4*)(bias + q);
    float ax = b.x + h.x * s, ay = b.y + h.y * s, az = b.z + h.z * s, aw = b.w + h.w * s;

    const int end = rowptr[n + 1];
    for (int i = rowptr[n]; i < end; ++i) {
        int s0 = csr_src[i];
        float w0 = csr_w[i];
        const float4 v = *(const float4*)(H16 + (size_t)s0 * 16 + q);
        ax += w0 * v.x; ay += w0 * v.y; az += w0 * v.z; aw += w0 * v.w;
    }
    *(float4*)(OUT + (size_t)n * 16 + q) = make_float4(ax, ay, az, aw);
}

// ---------------- mean pool ----------------

__global__ __launch_bounds__(256) void k_pool_zero(float* __restrict__ pool,
                                                   float* __restrict__ cnt) {
    int i = blockIdx.x * 256 + threadIdx.x;
    if (i < NGRAPH * NCLS) pool[i] = 0.f;
    if (i < NGRAPH) cnt[i] = 0.f;
}

__global__ __launch_bounds__(256) void k_pool(const float* __restrict__ H4,
                                              const int* __restrict__ batch,
                                              float* __restrict__ pool,
                                              float* __restrict__ cnt) {
    __shared__ float ps[NGRAPH][NCLS];
    __shared__ float pc[NGRAPH];
    for (int i = threadIdx.x; i < NGRAPH * NCLS; i += 256) ((float*)ps)[i] = 0.f;
    if (threadIdx.x < NGRAPH) pc[threadIdx.x] = 0.f;
    __syncthreads();
    int n = blockIdx.x * 256 + threadIdx.x;
    if (n < N_NODES) {
        int g = batch[n];
        const float4* hp = (const float4*)(H4 + (size_t)n * 16);
        float4 a = hp[0], b = hp[1], c = hp[2], d = hp[3];
        atomicAdd(&ps[g][0],  a.x); atomicAdd(&ps[g][1],  a.y);
        atomicAdd(&ps[g][2],  a.z); atomicAdd(&ps[g][3],  a.w);
        atomicAdd(&ps[g][4],  b.x); atomicAdd(&ps[g][5],  b.y);
        atomicAdd(&ps[g][6],  b.z); atomicAdd(&ps[g][7],  b.w);
        atomicAdd(&ps[g][8],  c.x); atomicAdd(&ps[g][9],  c.y);
        atomicAdd(&ps[g][10], c.z); atomicAdd(&ps[g][11], c.w);
        atomicAdd(&ps[g][12], d.x); atomicAdd(&ps[g][13], d.y);
        atomicAdd(&ps[g][14], d.z); atomicAdd(&ps[g][15], d.w);
        atomicAdd(&pc[g], 1.f);
    }
    __syncthreads();
    for (int i = threadIdx.x; i < NGRAPH * NCLS; i += 256)
        unsafeAtomicAdd(&pool[i], ((float*)ps)[i]);
    if (threadIdx.x < NGRAPH) unsafeAtomicAdd(&cnt[threadIdx.x], pc[threadIdx.x]);
}

__global__ __launch_bounds__(256) void k_final(const float* __restrict__ pool,
                                               const float* __restrict__ cnt,
                                               float* __restrict__ out) {
    int i = blockIdx.x * 256 + threadIdx.x;
    if (i < NGRAPH * NCLS) out[i] = pool[i] / fmaxf(cnt[i >> 4], 1.f);
}

// ---------------- host ----------------

extern "C" void kernel_launch(void* const* d_in, const int* in_sizes, int n_in,
                              void* d_out, int out_size, void* d_ws, size_t ws_size,
                              hipStream_t stream) {
    const float* x   = (const float*)d_in[0];
    const int*   ei  = (const int*)d_in[1];
    const int*   bvec= (const int*)d_in[2];
    const float* W1  = (const float*)d_in[3];
    const float* b1  = (const float*)d_in[4];
    const float* W2  = (const float*)d_in[5];
    const float* b2  = (const float*)d_in[6];
    const float* W3  = (const float*)d_in[7];
    const float* b3  = (const float*)d_in[8];
    const float* W4  = (const float*)d_in[9];
    const float* b4  = (const float*)d_in[10];
    float* out = (float*)d_out;

    const int* src = ei;
    const int* dst = ei + N_EDGES;

    const size_t NF = (size_t)N_NODES * F;          // 12.8M elems
    float* ws = (float*)d_ws;
    ushort* XA = (ushort*)ws;                        // NF bf16 (x cast; reused)
    ushort* XB = XA + NF;                            // NF bf16
    ushort* Hg = XB + NF;                            // NF bf16 (GEMM out)
    float*  G16 = (float*)(Hg + NF);                 // N*16 f32
    float*  H4  = G16 + (size_t)N_NODES * 16;        // N*16 f32
    float* aux  = H4 + (size_t)N_NODES * 16;
    int*   ecnt   = (int*)aux;                       // N
    float* dinv   = aux + N_NODES;                   // N
    int*   rowptr = (int*)(aux + 2 * N_NODES);       // N+1 (+pad)
    int*   cursor = (int*)(aux + 3 * N_NODES + 64);  // N
    int*   blkSum = (int*)(aux + 4 * N_NODES + 64);  // 256
    int*   blkOff = blkSum + 256;                    // 256
    int*   csr_src= blkOff + 256;                    // E
    float* csr_w  = (float*)(csr_src + N_EDGES);     // E
    float* pool   = csr_w + N_EDGES;                 // 1024
    float* cnt    = pool + NGRAPH * NCLS;            // 64
    ushort* Wp1   = (ushort*)(cnt + NGRAPH);         // 65536 each
    ushort* Wp2   = Wp1 + 65536;
    ushort* Wp3   = Wp2 + 65536;

    const int BN = NBLK_N;                       // 196
    const int BE = (N_EDGES + 255) / 256;        // 3125
    const int BG = (N_NODES * 64 + 255) / 256;   // 12500 (wave/node)
    const int BM = (N_NODES + 63) / 64;          // 782 MFMA blocks
    const int BC = (int)((NF / 8 + 255) / 256);  // cast blocks

    // ---- casts & weight packs
    k_cast_bf16<<<BC, 256, 0, stream>>>(x, XA, (int)(NF / 8));
    k_wpack<<<32, 256, 0, stream>>>(W1, Wp1);
    k_wpack<<<32, 256, 0, stream>>>(W2, Wp2);
    k_wpack<<<32, 256, 0, stream>>>(W3, Wp3);

    // ---- CSR build + norms
    k_zero_int<<<BN, 256, 0, stream>>>(ecnt, N_NODES);
    k_count<<<BE, 256, 0, stream>>>(dst, ecnt);
    k_dinv<<<BN, 256, 0, stream>>>(ecnt, dinv);
    k_scan_block<<<BN, 256, 0, stream>>>(ecnt, rowptr, blkSum);
    k_scan_tops<<<1, 256, 0, stream>>>(blkSum, blkOff);
    k_scan_add<<<BN, 256, 0, stream>>>(rowptr, blkOff, cursor);
    k_fill_csr<<<BE, 256, 0, stream>>>(src, dst, dinv, cursor, csr_src, csr_w);

    // ---- layer 1: Hg = XA@W1; XB = relu(agg(Hg))
    k_mfma256<<<BM, 256, 0, stream>>>(XA, Wp1, Hg);
    k_gather256<1><<<BG, 256, 0, stream>>>(Hg, b1, dinv, rowptr, csr_src, csr_w, nullptr, XB);

    // ---- layer 2: Hg = XB@W2; XA = relu(relu(agg(Hg)) + XB)
    k_mfma256<<<BM, 256, 0, stream>>>(XB, Wp2, Hg);
    k_gather256<2><<<BG, 256, 0, stream>>>(Hg, b2, dinv, rowptr, csr_src, csr_w, XB, XA);

    // ---- layer 3: Hg = XA@W3; XB = relu(relu(agg(Hg)) + XA)
    k_mfma256<<<BM, 256, 0, stream>>>(XA, Wp3, Hg);
    k_gather256<2><<<BG, 256, 0, stream>>>(Hg, b3, dinv, rowptr, csr_src, csr_w, XA, XB);

    // ---- layer 4: G16 = XB@W4; H4 = agg16(G16)
    k_gemm16<<<BN, 256, 0, stream>>>(XB, W4, G16);
    k_gather16<<<(N_NODES * 4 + 255) / 256, 256, 0, stream>>>(G16, b4, dinv, rowptr, csr_src, csr_w, H4);

    // ---- mean pool
    k_pool_zero<<<5, 256, 0, stream>>>(pool, cnt);
    k_pool<<<BN, 256, 0, stream>>>(H4, bvec, pool, cnt);
    k_final<<<4, 256, 0, stream>>>(pool, cnt, out);
}